// Round 1
// baseline (4656.411 us; speedup 1.0000x reference)
//
#include <hip/hip_runtime.h>

#define NGRAPH 64
#define HDIM 128

// ---------------- init: dinv=1 (self-loop), zero pool accumulators ----------------
__global__ __launch_bounds__(256) void k_init(float* dinv, float* sums, float* cnt, int N) {
  int i = blockIdx.x * 256 + threadIdx.x;
  if (i < N) dinv[i] = 1.0f;
  if (i < NGRAPH * HDIM) sums[i] = 0.0f;
  if (i < NGRAPH) cnt[i] = 0.0f;
}

// ---------------- degree histogram over dst ----------------
__global__ __launch_bounds__(256) void k_deg(const int* __restrict__ ei, float* dinv, int E) {
  int e = blockIdx.x * 256 + threadIdx.x;
  if (e < E) unsafeAtomicAdd(&dinv[ei[E + e]], 1.0f);
}

__global__ __launch_bounds__(256) void k_rsqrt(float* dinv, int N) {
  int i = blockIdx.x * 256 + threadIdx.x;
  if (i < N) dinv[i] = rsqrtf(dinv[i]);
}

// ---------------- C[N,128] = A[N,128] @ W[128,128]  (fp32, LDS-tiled) ----------------
// block = 256 threads, tile BM=64 rows x BN=128 cols, BK=64 (2 chunks).
// thread tile 8 rows x 4 cols.
__global__ __launch_bounds__(256) void k_gemm(const float* __restrict__ A,
                                              const float* __restrict__ W,
                                              float* __restrict__ C, int N) {
  __shared__ float Ws[64][128];   // [k][col]
  __shared__ float As[64][64];    // [k][row]  (transposed for b128 reads)
  const int tid = threadIdx.x;
  const int tx = tid & 31;        // col group: cols tx*4 .. tx*4+3
  const int ty = tid >> 5;        // row group: rows ty*8 .. ty*8+7
  const int row0 = blockIdx.x * 64;

  float acc[8][4];
#pragma unroll
  for (int i = 0; i < 8; ++i)
#pragma unroll
    for (int j = 0; j < 4; ++j) acc[i][j] = 0.0f;

  for (int kc = 0; kc < 2; ++kc) {
    // load W chunk: 64x128 floats (8 float4 per thread, coalesced)
#pragma unroll
    for (int i = 0; i < 8; ++i) {
      int flat = tid + i * 256;          // quad index 0..2047
      int k = flat >> 5;
      int c4 = (flat & 31) * 4;
      *(float4*)&Ws[k][c4] = *(const float4*)&W[(kc * 64 + k) * 128 + c4];
    }
    // load A chunk transposed: rows row0..row0+63, k-cols kc*64..+63
#pragma unroll
    for (int i = 0; i < 4; ++i) {
      int flat = tid + i * 256;          // 0..1023 (64 rows x 16 quads)
      int r = flat & 63;
      int kq = (flat >> 6) * 4;
      int row = row0 + r;
      float4 a;
      if (row < N) a = *(const float4*)&A[row * 128 + kc * 64 + kq];
      else { a.x = a.y = a.z = a.w = 0.0f; }
      As[kq + 0][r] = a.x;
      As[kq + 1][r] = a.y;
      As[kq + 2][r] = a.z;
      As[kq + 3][r] = a.w;
    }
    __syncthreads();
#pragma unroll
    for (int k = 0; k < 64; ++k) {
      float4 w = *(float4*)&Ws[k][tx * 4];
      float4 alo = *(float4*)&As[k][ty * 8];
      float4 ahi = *(float4*)&As[k][ty * 8 + 4];
      float av[8] = {alo.x, alo.y, alo.z, alo.w, ahi.x, ahi.y, ahi.z, ahi.w};
#pragma unroll
      for (int i = 0; i < 8; ++i) {
        acc[i][0] = fmaf(av[i], w.x, acc[i][0]);
        acc[i][1] = fmaf(av[i], w.y, acc[i][1]);
        acc[i][2] = fmaf(av[i], w.z, acc[i][2]);
        acc[i][3] = fmaf(av[i], w.w, acc[i][3]);
      }
    }
    __syncthreads();
  }
#pragma unroll
  for (int i = 0; i < 8; ++i) {
    int row = row0 + ty * 8 + i;
    if (row < N) {
      float4 o;
      o.x = acc[i][0]; o.y = acc[i][1]; o.z = acc[i][2]; o.w = acc[i][3];
      *(float4*)&C[row * 128 + tx * 4] = o;
    }
  }
}

// ---------------- agg = xw * (1/deg)  (self-loop term; also initializes agg) ------
__global__ __launch_bounds__(256) void k_agg_init(const float* __restrict__ xw,
                                                  const float* __restrict__ dinv,
                                                  float* __restrict__ agg, int N) {
  int t = blockIdx.x * 256 + threadIdx.x;
  if (t >= N * 32) return;
  int n = t >> 5, q = (t & 31) * 4;
  float di = dinv[n];
  float s = di * di;               // 1/deg
  float4 v = *(const float4*)&xw[n * 128 + q];
  v.x *= s; v.y *= s; v.z *= s; v.w *= s;
  *(float4*)&agg[n * 128 + q] = v;
}

// ---------------- edge scatter: agg[dst] += xw[src] * dinv[src]*dinv[dst] ---------
__global__ __launch_bounds__(256) void k_scatter(const int* __restrict__ ei,
                                                 const float* __restrict__ xw,
                                                 const float* __restrict__ dinv,
                                                 float* __restrict__ agg, int E) {
  int t = blockIdx.x * 256 + threadIdx.x;
  if (t >= E * 32) return;
  int e = t >> 5, q = (t & 31) * 4;
  int src = ei[e];
  int dst = ei[E + e];
  float nrm = dinv[src] * dinv[dst];
  float4 v = *(const float4*)&xw[src * 128 + q];
  float* base = &agg[dst * 128 + q];
  unsafeAtomicAdd(base + 0, v.x * nrm);
  unsafeAtomicAdd(base + 1, v.y * nrm);
  unsafeAtomicAdd(base + 2, v.z * nrm);
  unsafeAtomicAdd(base + 3, v.w * nrm);
}

// ---------------- h = relu(agg + b)  (in-place ok) ----------------
__global__ __launch_bounds__(256) void k_finalize(float* __restrict__ agg,
                                                  const float* __restrict__ b, int N) {
  int t = blockIdx.x * 256 + threadIdx.x;
  if (t >= N * 32) return;
  int n = t >> 5, q = (t & 31) * 4;
  float4 v = *(float4*)&agg[n * 128 + q];
  v.x = fmaxf(v.x + b[q + 0], 0.0f);
  v.y = fmaxf(v.y + b[q + 1], 0.0f);
  v.z = fmaxf(v.z + b[q + 2], 0.0f);
  v.w = fmaxf(v.w + b[q + 3], 0.0f);
  *(float4*)&agg[n * 128 + q] = v;
}

// ---------------- global mean pool (sums + counts via atomics) ----------------
__global__ __launch_bounds__(256) void k_pool(const float* __restrict__ h,
                                              const int* __restrict__ batch,
                                              float* __restrict__ sums,
                                              float* __restrict__ cnt, int N) {
  int t = blockIdx.x * 256 + threadIdx.x;
  if (t >= N * 32) return;
  int n = t >> 5, q = (t & 31) * 4;
  int g = batch[n];
  float4 v = *(const float4*)&h[n * 128 + q];
  float* base = &sums[g * 128 + q];
  unsafeAtomicAdd(base + 0, v.x);
  unsafeAtomicAdd(base + 1, v.y);
  unsafeAtomicAdd(base + 2, v.z);
  unsafeAtomicAdd(base + 3, v.w);
  if (q == 0) unsafeAtomicAdd(&cnt[g], 1.0f);
}

// ---------------- head: out[g,c] = (sums[g]/max(cnt,1)) @ Wc + bc ----------------
__global__ __launch_bounds__(640) void k_head(const float* __restrict__ sums,
                                              const float* __restrict__ cnt,
                                              const float* __restrict__ Wc,
                                              const float* __restrict__ bc,
                                              float* __restrict__ out) {
  int t = threadIdx.x;              // 640 = 64 graphs x 10 classes
  int g = t / 10, c = t % 10;
  float inv = 1.0f / fmaxf(cnt[g], 1.0f);
  float acc = 0.0f;
  for (int h = 0; h < 128; ++h)
    acc = fmaf(sums[g * 128 + h], Wc[h * 10 + c], acc);
  out[t] = acc * inv + bc[c];
}

extern "C" void kernel_launch(void* const* d_in, const int* in_sizes, int n_in,
                              void* d_out, int out_size, void* d_ws, size_t ws_size,
                              hipStream_t stream) {
  const float* x   = (const float*)d_in[0];
  const int*   ei  = (const int*)d_in[1];
  const int*   bat = (const int*)d_in[2];
  const float* W1  = (const float*)d_in[3];
  const float* b1  = (const float*)d_in[4];
  const float* W2  = (const float*)d_in[5];
  const float* b2  = (const float*)d_in[6];
  const float* W3  = (const float*)d_in[7];
  const float* b3  = (const float*)d_in[8];
  const float* Wc  = (const float*)d_in[9];
  const float* bc  = (const float*)d_in[10];

  const int N = in_sizes[0] / 128;
  const int E = in_sizes[1] / 2;

  float* ws   = (float*)d_ws;
  float* dinv = ws;                                   // N
  float* sums = ws + N;                               // 64*128
  float* cnt  = sums + NGRAPH * HDIM;                 // 64
  size_t off  = (size_t)((N + NGRAPH * HDIM + NGRAPH + 15) & ~15);
  float* B1   = ws + off;                             // N*128 (xw)
  float* B2   = B1 + (size_t)N * 128;                 // N*128 (agg / h)

  const int nb_N   = (N + 255) / 256;
  const int nb_NH  = (N * 32 + 255) / 256;
  const int nb_E   = (E + 255) / 256;
  const int nb_EH  = (E * 32 + 255) / 256;
  const int nb_gem = (N + 63) / 64;

  k_init<<<nb_N, 256, 0, stream>>>(dinv, sums, cnt, N);
  k_deg<<<nb_E, 256, 0, stream>>>(ei, dinv, E);
  k_rsqrt<<<nb_N, 256, 0, stream>>>(dinv, N);

  const float* in_ptr = x;
  const float* Wl[3] = {W1, W2, W3};
  const float* bl[3] = {b1, b2, b3};
  for (int L = 0; L < 3; ++L) {
    k_gemm<<<nb_gem, 256, 0, stream>>>(in_ptr, Wl[L], B1, N);
    k_agg_init<<<nb_NH, 256, 0, stream>>>(B1, dinv, B2, N);
    k_scatter<<<nb_EH, 256, 0, stream>>>(ei, B1, dinv, B2, E);
    k_finalize<<<nb_NH, 256, 0, stream>>>(B2, bl[L], N);
    in_ptr = B2;
  }

  k_pool<<<nb_NH, 256, 0, stream>>>(B2, bat, sums, cnt, N);
  k_head<<<1, 640, 0, stream>>>(sums, cnt, Wc, bc, (float*)d_out);
}

// Round 2
// 957.338 us; speedup vs baseline: 4.8639x; 4.8639x over previous
//
#include <hip/hip_runtime.h>

#define NGRAPH 64
#define HDIM 128

// ---------------- zero int degree + pool accumulators ----------------
__global__ __launch_bounds__(256) void k_zero(int* deg, float* sums, float* cnt, int N) {
  int i = blockIdx.x * 256 + threadIdx.x;
  if (i < N) deg[i] = 0;
  if (i < NGRAPH * HDIM) sums[i] = 0.0f;
  if (i < NGRAPH) cnt[i] = 0.0f;
}

// ---------------- degree histogram over dst (int atomics) ----------------
__global__ __launch_bounds__(256) void k_hist(const int* __restrict__ ei, int* deg, int E) {
  int e = blockIdx.x * 256 + threadIdx.x;
  if (e < E) atomicAdd(&deg[ei[E + e]], 1);
}

// ---------------- scan pass 1: per-block exclusive scan of deg ----------------
__global__ __launch_bounds__(256) void k_scan1(const int* __restrict__ deg,
                                               int* __restrict__ rowptr,
                                               int* __restrict__ bsum, int N) {
  __shared__ int s[256];
  int tid = threadIdx.x;
  int i = blockIdx.x * 256 + tid;
  int v = (i < N) ? deg[i] : 0;
  s[tid] = v;
  __syncthreads();
#pragma unroll
  for (int off = 1; off < 256; off <<= 1) {
    int t = (tid >= off) ? s[tid - off] : 0;
    __syncthreads();
    s[tid] += t;
    __syncthreads();
  }
  if (i < N) rowptr[i] = s[tid] - v;       // exclusive
  if (tid == 255) bsum[blockIdx.x] = s[255];
}

// ---------------- scan pass 2: exclusive scan of block sums (single block) -------
__global__ __launch_bounds__(256) void k_scan2(int* __restrict__ bsum, int nb) {
  __shared__ int s[256];
  int tid = threadIdx.x;
  int v = (tid < nb) ? bsum[tid] : 0;
  s[tid] = v;
  __syncthreads();
#pragma unroll
  for (int off = 1; off < 256; off <<= 1) {
    int t = (tid >= off) ? s[tid - off] : 0;
    __syncthreads();
    s[tid] += t;
    __syncthreads();
  }
  if (tid < nb) bsum[tid] = s[tid] - v;    // exclusive
}

// ------- scan pass 3: add block offset; init cursor; dinv = rsqrt(deg+1) --------
__global__ __launch_bounds__(256) void k_scan3(const int* __restrict__ deg,
                                               int* __restrict__ rowptr,
                                               const int* __restrict__ bsum,
                                               int* __restrict__ cursor,
                                               float* __restrict__ dinv, int N, int E) {
  int i = blockIdx.x * 256 + threadIdx.x;
  if (i < N) {
    int r = rowptr[i] + bsum[i >> 8];
    rowptr[i] = r;
    cursor[i] = r;
    dinv[i] = rsqrtf((float)deg[i] + 1.0f);
  }
  if (i == 0) rowptr[N] = E;
}

// ---------------- CSR fill: col[pos] = src, sorted by dst ----------------
__global__ __launch_bounds__(256) void k_fill(const int* __restrict__ ei,
                                              int* __restrict__ cursor,
                                              int* __restrict__ col, int E) {
  int e = blockIdx.x * 256 + threadIdx.x;
  if (e < E) {
    int pos = atomicAdd(&cursor[ei[E + e]], 1);
    col[pos] = ei[e];
  }
}

// ---------------- C[N,128] = A[N,128] @ W[128,128]  (fp32, LDS-tiled) ----------------
__global__ __launch_bounds__(256) void k_gemm(const float* __restrict__ A,
                                              const float* __restrict__ W,
                                              float* __restrict__ C, int N) {
  __shared__ float Ws[64][128];   // [k][col]
  __shared__ float As[64][64];    // [k][row]
  const int tid = threadIdx.x;
  const int tx = tid & 31;
  const int ty = tid >> 5;
  const int row0 = blockIdx.x * 64;

  float acc[8][4];
#pragma unroll
  for (int i = 0; i < 8; ++i)
#pragma unroll
    for (int j = 0; j < 4; ++j) acc[i][j] = 0.0f;

  for (int kc = 0; kc < 2; ++kc) {
#pragma unroll
    for (int i = 0; i < 8; ++i) {
      int flat = tid + i * 256;
      int k = flat >> 5;
      int c4 = (flat & 31) * 4;
      *(float4*)&Ws[k][c4] = *(const float4*)&W[(kc * 64 + k) * 128 + c4];
    }
#pragma unroll
    for (int i = 0; i < 4; ++i) {
      int flat = tid + i * 256;
      int r = flat & 63;
      int kq = (flat >> 6) * 4;
      int row = row0 + r;
      float4 a;
      if (row < N) a = *(const float4*)&A[row * 128 + kc * 64 + kq];
      else { a.x = a.y = a.z = a.w = 0.0f; }
      As[kq + 0][r] = a.x;
      As[kq + 1][r] = a.y;
      As[kq + 2][r] = a.z;
      As[kq + 3][r] = a.w;
    }
    __syncthreads();
#pragma unroll
    for (int k = 0; k < 64; ++k) {
      float4 w = *(float4*)&Ws[k][tx * 4];
      float4 alo = *(float4*)&As[k][ty * 8];
      float4 ahi = *(float4*)&As[k][ty * 8 + 4];
      float av[8] = {alo.x, alo.y, alo.z, alo.w, ahi.x, ahi.y, ahi.z, ahi.w};
#pragma unroll
      for (int i = 0; i < 8; ++i) {
        acc[i][0] = fmaf(av[i], w.x, acc[i][0]);
        acc[i][1] = fmaf(av[i], w.y, acc[i][1]);
        acc[i][2] = fmaf(av[i], w.z, acc[i][2]);
        acc[i][3] = fmaf(av[i], w.w, acc[i][3]);
      }
    }
    __syncthreads();
  }
#pragma unroll
  for (int i = 0; i < 8; ++i) {
    int row = row0 + ty * 8 + i;
    if (row < N) {
      float4 o;
      o.x = acc[i][0]; o.y = acc[i][1]; o.z = acc[i][2]; o.w = acc[i][3];
      *(float4*)&C[row * 128 + tx * 4] = o;
    }
  }
}

// -------- fused gather: h[n] = relu(dinv[n]*(sum_e dinv[src]*xw[src] + dinv[n]*xw[n]) + b)
// one wave per node, lane owns 2 columns (float2), 4 waves per block
__global__ __launch_bounds__(256) void k_gather(const int* __restrict__ rowptr,
                                                const int* __restrict__ col,
                                                const float* __restrict__ xw,
                                                const float* __restrict__ dinv,
                                                const float* __restrict__ b,
                                                float* __restrict__ h, int N) {
  int node = blockIdx.x * 4 + (threadIdx.x >> 6);
  if (node >= N) return;
  int lane = threadIdx.x & 63;
  int c = lane * 2;
  int beg = rowptr[node], end = rowptr[node + 1];

  float ax = 0.0f, ay = 0.0f;
  int e = beg;
  for (; e + 1 < end; e += 2) {
    int s0 = col[e], s1 = col[e + 1];
    float w0 = dinv[s0], w1 = dinv[s1];
    float2 v0 = *(const float2*)&xw[(size_t)s0 * 128 + c];
    float2 v1 = *(const float2*)&xw[(size_t)s1 * 128 + c];
    ax = fmaf(v0.x, w0, ax); ay = fmaf(v0.y, w0, ay);
    ax = fmaf(v1.x, w1, ax); ay = fmaf(v1.y, w1, ay);
  }
  if (e < end) {
    int s0 = col[e];
    float w0 = dinv[s0];
    float2 v0 = *(const float2*)&xw[(size_t)s0 * 128 + c];
    ax = fmaf(v0.x, w0, ax); ay = fmaf(v0.y, w0, ay);
  }
  float dn = dinv[node];
  float2 self = *(const float2*)&xw[(size_t)node * 128 + c];
  ax = (ax + dn * self.x) * dn;
  ay = (ay + dn * self.y) * dn;
  float2 o;
  o.x = fmaxf(ax + b[c], 0.0f);
  o.y = fmaxf(ay + b[c + 1], 0.0f);
  *(float2*)&h[(size_t)node * 128 + c] = o;
}

// ---------------- global mean pool (sums + counts via atomics) ----------------
__global__ __launch_bounds__(256) void k_pool(const float* __restrict__ h,
                                              const int* __restrict__ batch,
                                              float* __restrict__ sums,
                                              float* __restrict__ cnt, int N) {
  int t = blockIdx.x * 256 + threadIdx.x;
  if (t >= N * 32) return;
  int n = t >> 5, q = (t & 31) * 4;
  int g = batch[n];
  float4 v = *(const float4*)&h[(size_t)n * 128 + q];
  float* base = &sums[g * 128 + q];
  unsafeAtomicAdd(base + 0, v.x);
  unsafeAtomicAdd(base + 1, v.y);
  unsafeAtomicAdd(base + 2, v.z);
  unsafeAtomicAdd(base + 3, v.w);
  if (q == 0) unsafeAtomicAdd(&cnt[g], 1.0f);
}

// ---------------- head ----------------
__global__ __launch_bounds__(640) void k_head(const float* __restrict__ sums,
                                              const float* __restrict__ cnt,
                                              const float* __restrict__ Wc,
                                              const float* __restrict__ bc,
                                              float* __restrict__ out) {
  int t = threadIdx.x;
  int g = t / 10, c = t % 10;
  float inv = 1.0f / fmaxf(cnt[g], 1.0f);
  float acc = 0.0f;
  for (int h = 0; h < 128; ++h)
    acc = fmaf(sums[g * 128 + h], Wc[h * 10 + c], acc);
  out[t] = acc * inv + bc[c];
}

extern "C" void kernel_launch(void* const* d_in, const int* in_sizes, int n_in,
                              void* d_out, int out_size, void* d_ws, size_t ws_size,
                              hipStream_t stream) {
  const float* x   = (const float*)d_in[0];
  const int*   ei  = (const int*)d_in[1];
  const int*   bat = (const int*)d_in[2];
  const float* W1  = (const float*)d_in[3];
  const float* b1  = (const float*)d_in[4];
  const float* W2  = (const float*)d_in[5];
  const float* b2  = (const float*)d_in[6];
  const float* W3  = (const float*)d_in[7];
  const float* b3  = (const float*)d_in[8];
  const float* Wc  = (const float*)d_in[9];
  const float* bc  = (const float*)d_in[10];

  const int N = in_sizes[0] / 128;
  const int E = in_sizes[1] / 2;

  // workspace layout (4-byte units)
  char* wsb = (char*)d_ws;
  int*   deg    = (int*)wsb;                      wsb += (size_t)N * 4;
  int*   rowptr = (int*)wsb;                      wsb += (size_t)(N + 1) * 4;
  int*   cursor = (int*)wsb;                      wsb += (size_t)N * 4;
  int*   bsum   = (int*)wsb;                      wsb += 256 * 4;
  float* dinv   = (float*)wsb;                    wsb += (size_t)N * 4;
  int*   col    = (int*)wsb;                      wsb += (size_t)E * 4;
  float* sums   = (float*)wsb;                    wsb += NGRAPH * HDIM * 4;
  float* cnt    = (float*)wsb;                    wsb += NGRAPH * 4;
  wsb = (char*)(((size_t)wsb + 255) & ~(size_t)255);
  float* B1     = (float*)wsb;                    wsb += (size_t)N * 128 * 4;
  float* B2     = (float*)wsb;

  const int nb_N   = (N + 255) / 256;
  const int nb_NH  = (N * 32 + 255) / 256;
  const int nb_E   = (E + 255) / 256;
  const int nb_gem = (N + 63) / 64;
  const int nb_gat = (N + 3) / 4;

  // CSR build (once per call, reused for all 3 layers)
  k_zero<<<nb_N, 256, 0, stream>>>(deg, sums, cnt, N);
  k_hist<<<nb_E, 256, 0, stream>>>(ei, deg, E);
  k_scan1<<<nb_N, 256, 0, stream>>>(deg, rowptr, bsum, N);
  k_scan2<<<1, 256, 0, stream>>>(bsum, nb_N);
  k_scan3<<<nb_N, 256, 0, stream>>>(deg, rowptr, bsum, cursor, dinv, N, E);
  k_fill<<<nb_E, 256, 0, stream>>>(ei, cursor, col, E);

  const float* in_ptr = x;
  const float* Wl[3] = {W1, W2, W3};
  const float* bl[3] = {b1, b2, b3};
  for (int L = 0; L < 3; ++L) {
    k_gemm<<<nb_gem, 256, 0, stream>>>(in_ptr, Wl[L], B1, N);
    k_gather<<<nb_gat, 256, 0, stream>>>(rowptr, col, B1, dinv, bl[L], B2, N);
    in_ptr = B2;
  }

  k_pool<<<nb_NH, 256, 0, stream>>>(B2, bat, sums, cnt, N);
  k_head<<<1, 640, 0, stream>>>(sums, cnt, Wc, bc, (float*)d_out);
}

// Round 3
// 527.144 us; speedup vs baseline: 8.8333x; 1.8161x over previous
//
#include <hip/hip_runtime.h>

#define NGRAPH 64
#define HDIM 128
#define POOL_RS 8

// ---------------- zero int degree + pool accumulators ----------------
__global__ __launch_bounds__(256) void k_zero(int* deg, float* sums, int N) {
  int i = blockIdx.x * 256 + threadIdx.x;
  if (i < N) deg[i] = 0;
  if (i < NGRAPH * HDIM) sums[i] = 0.0f;
}

// ---------------- degree histogram over dst (int atomics) ----------------
__global__ __launch_bounds__(256) void k_hist(const int* __restrict__ ei, int* deg, int E) {
  int e = blockIdx.x * 256 + threadIdx.x;
  if (e < E) atomicAdd(&deg[ei[E + e]], 1);
}

// ---------------- scan pass 1: per-block exclusive scan of deg ----------------
__global__ __launch_bounds__(256) void k_scan1(const int* __restrict__ deg,
                                               int* __restrict__ rowptr,
                                               int* __restrict__ bsum, int N) {
  __shared__ int s[256];
  int tid = threadIdx.x;
  int i = blockIdx.x * 256 + tid;
  int v = (i < N) ? deg[i] : 0;
  s[tid] = v;
  __syncthreads();
#pragma unroll
  for (int off = 1; off < 256; off <<= 1) {
    int t = (tid >= off) ? s[tid - off] : 0;
    __syncthreads();
    s[tid] += t;
    __syncthreads();
  }
  if (i < N) rowptr[i] = s[tid] - v;       // exclusive
  if (tid == 255) bsum[blockIdx.x] = s[255];
}

// ---------------- scan pass 2: exclusive scan of block sums (single block) -------
__global__ __launch_bounds__(256) void k_scan2(int* __restrict__ bsum, int nb) {
  __shared__ int s[256];
  int tid = threadIdx.x;
  int v = (tid < nb) ? bsum[tid] : 0;
  s[tid] = v;
  __syncthreads();
#pragma unroll
  for (int off = 1; off < 256; off <<= 1) {
    int t = (tid >= off) ? s[tid - off] : 0;
    __syncthreads();
    s[tid] += t;
    __syncthreads();
  }
  if (tid < nb) bsum[tid] = s[tid] - v;    // exclusive
}

// ------- scan pass 3: add block offset; init cursor; dinv = rsqrt(deg+1) --------
__global__ __launch_bounds__(256) void k_scan3(const int* __restrict__ deg,
                                               int* __restrict__ rowptr,
                                               const int* __restrict__ bsum,
                                               int* __restrict__ cursor,
                                               float* __restrict__ dinv, int N, int E) {
  int i = blockIdx.x * 256 + threadIdx.x;
  if (i < N) {
    int r = rowptr[i] + bsum[i >> 8];
    rowptr[i] = r;
    cursor[i] = r;
    dinv[i] = rsqrtf((float)deg[i] + 1.0f);
  }
  if (i == 0) rowptr[N] = E;
}

// ---------------- CSR fill: col[pos] = src, sorted by dst ----------------
__global__ __launch_bounds__(256) void k_fill(const int* __restrict__ ei,
                                              int* __restrict__ cursor,
                                              int* __restrict__ col, int E) {
  int e = blockIdx.x * 256 + threadIdx.x;
  if (e < E) {
    int pos = atomicAdd(&cursor[ei[E + e]], 1);
    col[pos] = ei[e];
  }
}

// ------- graph boundaries from sorted batch: gstart[g] = first row of graph g -----
__global__ __launch_bounds__(256) void k_gbound(const int* __restrict__ bat,
                                                int* __restrict__ gstart, int N) {
  int i = blockIdx.x * 256 + threadIdx.x;
  if (i >= N) return;
  int b = bat[i];
  int prev = (i == 0) ? -1 : bat[i - 1];
  for (int g = prev + 1; g <= b; ++g) gstart[g] = i;
  if (i == N - 1)
    for (int g = b + 1; g <= NGRAPH; ++g) gstart[g] = N;
}

// ---------------- C[N,128] = A[N,128] @ W[128,128]  (fp32, LDS-tiled) ----------------
__global__ __launch_bounds__(256) void k_gemm(const float* __restrict__ A,
                                              const float* __restrict__ W,
                                              float* __restrict__ C, int N) {
  __shared__ float Ws[64][128];   // [k][col]
  __shared__ float As[64][64];    // [k][row]
  const int tid = threadIdx.x;
  const int tx = tid & 31;
  const int ty = tid >> 5;
  const int row0 = blockIdx.x * 64;

  float acc[8][4];
#pragma unroll
  for (int i = 0; i < 8; ++i)
#pragma unroll
    for (int j = 0; j < 4; ++j) acc[i][j] = 0.0f;

  for (int kc = 0; kc < 2; ++kc) {
#pragma unroll
    for (int i = 0; i < 8; ++i) {
      int flat = tid + i * 256;
      int k = flat >> 5;
      int c4 = (flat & 31) * 4;
      *(float4*)&Ws[k][c4] = *(const float4*)&W[(kc * 64 + k) * 128 + c4];
    }
#pragma unroll
    for (int i = 0; i < 4; ++i) {
      int flat = tid + i * 256;
      int r = flat & 63;
      int kq = (flat >> 6) * 4;
      int row = row0 + r;
      float4 a;
      if (row < N) a = *(const float4*)&A[row * 128 + kc * 64 + kq];
      else { a.x = a.y = a.z = a.w = 0.0f; }
      As[kq + 0][r] = a.x;
      As[kq + 1][r] = a.y;
      As[kq + 2][r] = a.z;
      As[kq + 3][r] = a.w;
    }
    __syncthreads();
#pragma unroll
    for (int k = 0; k < 64; ++k) {
      float4 w = *(float4*)&Ws[k][tx * 4];
      float4 alo = *(float4*)&As[k][ty * 8];
      float4 ahi = *(float4*)&As[k][ty * 8 + 4];
      float av[8] = {alo.x, alo.y, alo.z, alo.w, ahi.x, ahi.y, ahi.z, ahi.w};
#pragma unroll
      for (int i = 0; i < 8; ++i) {
        acc[i][0] = fmaf(av[i], w.x, acc[i][0]);
        acc[i][1] = fmaf(av[i], w.y, acc[i][1]);
        acc[i][2] = fmaf(av[i], w.z, acc[i][2]);
        acc[i][3] = fmaf(av[i], w.w, acc[i][3]);
      }
    }
    __syncthreads();
  }
#pragma unroll
  for (int i = 0; i < 8; ++i) {
    int row = row0 + ty * 8 + i;
    if (row < N) {
      float4 o;
      o.x = acc[i][0]; o.y = acc[i][1]; o.z = acc[i][2]; o.w = acc[i][3];
      *(float4*)&C[row * 128 + tx * 4] = o;
    }
  }
}

// -------- fused gather: h[n] = relu(dinv[n]*(sum_e dinv[src]*xw[src] + dinv[n]*xw[n]) + b)
__global__ __launch_bounds__(256) void k_gather(const int* __restrict__ rowptr,
                                                const int* __restrict__ col,
                                                const float* __restrict__ xw,
                                                const float* __restrict__ dinv,
                                                const float* __restrict__ b,
                                                float* __restrict__ h, int N) {
  int node = blockIdx.x * 4 + (threadIdx.x >> 6);
  if (node >= N) return;
  int lane = threadIdx.x & 63;
  int c = lane * 2;
  int beg = rowptr[node], end = rowptr[node + 1];

  float ax = 0.0f, ay = 0.0f;
  int e = beg;
  for (; e + 1 < end; e += 2) {
    int s0 = col[e], s1 = col[e + 1];
    float w0 = dinv[s0], w1 = dinv[s1];
    float2 v0 = *(const float2*)&xw[(size_t)s0 * 128 + c];
    float2 v1 = *(const float2*)&xw[(size_t)s1 * 128 + c];
    ax = fmaf(v0.x, w0, ax); ay = fmaf(v0.y, w0, ay);
    ax = fmaf(v1.x, w1, ax); ay = fmaf(v1.y, w1, ay);
  }
  if (e < end) {
    int s0 = col[e];
    float w0 = dinv[s0];
    float2 v0 = *(const float2*)&xw[(size_t)s0 * 128 + c];
    ax = fmaf(v0.x, w0, ax); ay = fmaf(v0.y, w0, ay);
  }
  float dn = dinv[node];
  float2 self = *(const float2*)&xw[(size_t)node * 128 + c];
  ax = (ax + dn * self.x) * dn;
  ay = (ay + dn * self.y) * dn;
  float2 o;
  o.x = fmaxf(ax + b[c], 0.0f);
  o.y = fmaxf(ay + b[c + 1], 0.0f);
  *(float2*)&h[(size_t)node * 128 + c] = o;
}

// ------- segmented mean-pool: grid (NGRAPH, POOL_RS); register + LDS reduce -------
__global__ __launch_bounds__(256) void k_pool(const float* __restrict__ h,
                                              const int* __restrict__ gstart,
                                              float* __restrict__ sums) {
  int g = blockIdx.x;
  int rs = blockIdx.y;
  int beg = gstart[g], end = gstart[g + 1];
  int tid = threadIdx.x;
  int ty = tid >> 5;            // 8 row groups
  int q = (tid & 31) * 4;       // col quad

  float4 acc; acc.x = acc.y = acc.z = acc.w = 0.0f;
  for (int r = beg + rs * 8 + ty; r < end; r += POOL_RS * 8) {
    float4 v = *(const float4*)&h[(size_t)r * 128 + q];
    acc.x += v.x; acc.y += v.y; acc.z += v.z; acc.w += v.w;
  }
  __shared__ float s[8][128];
  *(float4*)&s[ty][q] = acc;
  __syncthreads();
  if (tid < 32) {
    int qq = tid * 4;
    float4 t; t.x = t.y = t.z = t.w = 0.0f;
#pragma unroll
    for (int j = 0; j < 8; ++j) {
      float4 v = *(float4*)&s[j][qq];
      t.x += v.x; t.y += v.y; t.z += v.z; t.w += v.w;
    }
    float* base = &sums[g * 128 + qq];
    unsafeAtomicAdd(base + 0, t.x);
    unsafeAtomicAdd(base + 1, t.y);
    unsafeAtomicAdd(base + 2, t.z);
    unsafeAtomicAdd(base + 3, t.w);
  }
}

// ---------------- head: out[g,c] = (sums[g]/max(cnt,1)) @ Wc + bc ----------------
__global__ __launch_bounds__(640) void k_head(const float* __restrict__ sums,
                                              const int* __restrict__ gstart,
                                              const float* __restrict__ Wc,
                                              const float* __restrict__ bc,
                                              float* __restrict__ out) {
  int t = threadIdx.x;
  int g = t / 10, c = t % 10;
  float cntf = (float)(gstart[g + 1] - gstart[g]);
  float inv = 1.0f / fmaxf(cntf, 1.0f);
  float acc = 0.0f;
  for (int h = 0; h < 128; ++h)
    acc = fmaf(sums[g * 128 + h], Wc[h * 10 + c], acc);
  out[t] = acc * inv + bc[c];
}

extern "C" void kernel_launch(void* const* d_in, const int* in_sizes, int n_in,
                              void* d_out, int out_size, void* d_ws, size_t ws_size,
                              hipStream_t stream) {
  const float* x   = (const float*)d_in[0];
  const int*   ei  = (const int*)d_in[1];
  const int*   bat = (const int*)d_in[2];
  const float* W1  = (const float*)d_in[3];
  const float* b1  = (const float*)d_in[4];
  const float* W2  = (const float*)d_in[5];
  const float* b2  = (const float*)d_in[6];
  const float* W3  = (const float*)d_in[7];
  const float* b3  = (const float*)d_in[8];
  const float* Wc  = (const float*)d_in[9];
  const float* bc  = (const float*)d_in[10];

  const int N = in_sizes[0] / 128;
  const int E = in_sizes[1] / 2;

  // workspace layout
  char* wsb = (char*)d_ws;
  int*   deg    = (int*)wsb;                      wsb += (size_t)N * 4;
  int*   rowptr = (int*)wsb;                      wsb += (size_t)(N + 1) * 4;
  int*   cursor = (int*)wsb;                      wsb += (size_t)N * 4;
  int*   bsum   = (int*)wsb;                      wsb += 256 * 4;
  float* dinv   = (float*)wsb;                    wsb += (size_t)N * 4;
  int*   col    = (int*)wsb;                      wsb += (size_t)E * 4;
  float* sums   = (float*)wsb;                    wsb += NGRAPH * HDIM * 4;
  int*   gstart = (int*)wsb;                      wsb += (NGRAPH + 1) * 4;
  wsb = (char*)(((size_t)wsb + 255) & ~(size_t)255);
  float* B1     = (float*)wsb;                    wsb += (size_t)N * 128 * 4;
  float* B2     = (float*)wsb;

  const int nb_N   = (N + 255) / 256;
  const int nb_E   = (E + 255) / 256;
  const int nb_gem = (N + 63) / 64;
  const int nb_gat = (N + 3) / 4;

  // CSR build (once per call, reused for all 3 layers)
  k_zero<<<nb_N, 256, 0, stream>>>(deg, sums, N);
  k_hist<<<nb_E, 256, 0, stream>>>(ei, deg, E);
  k_scan1<<<nb_N, 256, 0, stream>>>(deg, rowptr, bsum, N);
  k_scan2<<<1, 256, 0, stream>>>(bsum, nb_N);
  k_scan3<<<nb_N, 256, 0, stream>>>(deg, rowptr, bsum, cursor, dinv, N, E);
  k_fill<<<nb_E, 256, 0, stream>>>(ei, cursor, col, E);
  k_gbound<<<nb_N, 256, 0, stream>>>(bat, gstart, N);

  const float* in_ptr = x;
  const float* Wl[3] = {W1, W2, W3};
  const float* bl[3] = {b1, b2, b3};
  for (int L = 0; L < 3; ++L) {
    k_gemm<<<nb_gem, 256, 0, stream>>>(in_ptr, Wl[L], B1, N);
    k_gather<<<nb_gat, 256, 0, stream>>>(rowptr, col, B1, dinv, bl[L], B2, N);
    in_ptr = B2;
  }

  dim3 pgrid(NGRAPH, POOL_RS);
  k_pool<<<pgrid, 256, 0, stream>>>(B2, gstart, sums);
  k_head<<<1, 640, 0, stream>>>(sums, gstart, Wc, bc, (float*)d_out);
}